// Round 1
// baseline (171.278 us; speedup 1.0000x reference)
//
#include <hip/hip_runtime.h>
#include <hip/hip_fp16.h>

#define BB 32
#define NN 512
#define DD 256
#define NEG_INF -9e15f

typedef _Float16 half8 __attribute__((ext_vector_type(8)));
typedef float v4f __attribute__((ext_vector_type(4)));

// ---------------- pre-kernel: fp32 -> fp16 convert + transpose ----------------
__global__ __launch_bounds__(256) void cvt_kernel(const float* __restrict__ h,
                                                  _Float16* __restrict__ h16,
                                                  _Float16* __restrict__ h16t) {
    __shared__ _Float16 tile[32][34];
    int d0 = blockIdx.x * 32;
    int n0 = blockIdx.y * 32;
    int b  = blockIdx.z;
    int c  = threadIdx.x & 31;   // inner (d on read, n on write)
    int r0 = threadIdx.x >> 5;   // 8 rows per pass
    for (int rr = r0; rr < 32; rr += 8) {
        float v = h[((size_t)b * NN + (n0 + rr)) * DD + d0 + c];
        _Float16 hv = (_Float16)v;
        h16[((size_t)b * NN + (n0 + rr)) * DD + d0 + c] = hv;
        tile[rr][c] = hv;
    }
    __syncthreads();
    for (int rr = r0; rr < 32; rr += 8) {
        // h16t[b][d0+rr][n0+c] = h[n0+c][d0+rr] = tile[c][rr]
        h16t[((size_t)b * DD + (d0 + rr)) * NN + n0 + c] = tile[c][rr];
    }
}

// ---------------- fused GAT kernel ----------------
// Grid: BB*(NN/32) blocks of 256 threads. Block = (b, 32-row i-block).
// Waves: it = wave>>1 (i-tile of 16), jh = wave&1 (j-half of 256).
__global__ __launch_bounds__(256, 2) void gat_kernel(
    const _Float16* __restrict__ h16,   // [B][N][D]
    const _Float16* __restrict__ h16t,  // [B][D][N]
    const int* __restrict__ adj,        // [B][N][N]
    const float* __restrict__ a0, const float* __restrict__ a1,
    const float* __restrict__ a2, const float* __restrict__ a3,
    float* __restrict__ out)            // [B][N][D]
{
    __shared__ _Float16 sA[4][DD];            // 2 KB: the 4 attention vectors
    __shared__ _Float16 sAlpha[32][NN + 8];   // 33.3 KB: unnormalized alpha, fp16
    __shared__ float sRedM[2][2][16];         // per-(it,jh) row-max partials
    __shared__ float sRedS[2][2][16];         // per-(it,jh) row-sum partials

    const int tid  = threadIdx.x;
    const int wave = tid >> 6;
    const int lane = tid & 63;
    const int c    = lane & 15;   // MFMA: A.m / B.n / C.col
    const int q    = lane >> 4;   // MFMA: k-quad; C.row = q*4+reg

    const int blk  = blockIdx.x;
    const int b    = blk >> 4;    // NN/32 = 16 i-blocks per batch
    const int iblk = blk & 15;
    const int i0   = iblk * 32;
    const int it   = wave >> 1;
    const int jh   = wave & 1;

    // stage a_k as fp16 (tid == d, blockDim == DD)
    sA[0][tid] = (_Float16)a0[tid];
    sA[1][tid] = (_Float16)a1[tid];
    sA[2][tid] = (_Float16)a2[tid];
    sA[3][tid] = (_Float16)a3[tid];
    __syncthreads();

    const _Float16* Hb   = h16 + (size_t)b * NN * DD;
    const int*      adjb = adj + (size_t)b * NN * NN;

    // hoist the A-side h fragments (row i0+it*16+c, all 8 K-steps): 32 VGPRs
    half8 hfrag[8];
    {
        const _Float16* hrow = Hb + (size_t)(i0 + it * 16 + c) * DD;
#pragma unroll
        for (int s = 0; s < 8; ++s)
            hfrag[s] = *(const half8*)(hrow + s * 32 + q * 8);
    }

    const int jbase = jh * 256;
    v4f S[16];   // selected scores for this wave's 16 rows x 256 j

    // ---------------- phase 1: scores (4 e_k via MFMA) + select + leaky ----------------
#pragma unroll
    for (int g = 0; g < 4; ++g) {
        const int jg0 = jbase + g * 64;
        v4f e[4][4];
#pragma unroll
        for (int k = 0; k < 4; ++k)
#pragma unroll
            for (int jt = 0; jt < 4; ++jt)
                e[k][jt] = (v4f){0.f, 0.f, 0.f, 0.f};

#pragma unroll
        for (int s = 0; s < 8; ++s) {
            half8 bfrag[4];
#pragma unroll
            for (int jt = 0; jt < 4; ++jt)
                bfrag[jt] = *(const half8*)(Hb + (size_t)(jg0 + jt * 16 + c) * DD + s * 32 + q * 8);
            half8 aw[4];
#pragma unroll
            for (int k = 0; k < 4; ++k)
                aw[k] = *(const half8*)(&sA[k][s * 32 + q * 8]);
#pragma unroll
            for (int k = 0; k < 4; ++k) {
                half8 af = hfrag[s] * aw[k];   // (h_i * a_k) on the fly, v_pk_mul_f16
#pragma unroll
                for (int jt = 0; jt < 4; ++jt)
                    e[k][jt] = __builtin_amdgcn_mfma_f32_16x16x32_f16(af, bfrag[jt], e[k][jt], 0, 0, 0);
            }
        }
        // adj-based selection + leaky_relu (leaky commutes with the select)
#pragma unroll
        for (int jt = 0; jt < 4; ++jt) {
            const int j = jg0 + jt * 16 + c;
#pragma unroll
            for (int r = 0; r < 4; ++r) {
                const int i = i0 + it * 16 + q * 4 + r;
                const int v = adjb[(size_t)i * NN + j];
                float sc = (v == 1) ? e[0][jt][r]
                         : (v == 2) ? e[1][jt][r]
                         : (v == 3) ? e[2][jt][r]
                         : (v == 4) ? e[3][jt][r] : NEG_INF;
                sc = sc > 0.f ? sc : 0.2f * sc;
                S[g * 4 + jt][r] = sc;
            }
        }
    }

    // ---------------- phase 2: softmax over j (cross-wave-pair) ----------------
    float m4[4];
#pragma unroll
    for (int r = 0; r < 4; ++r) {
        float m = S[0][r];
#pragma unroll
        for (int t = 1; t < 16; ++t) m = fmaxf(m, S[t][r]);
#pragma unroll
        for (int off = 1; off < 16; off <<= 1)
            m = fmaxf(m, __shfl_xor(m, off, 64));
        m4[r] = m;
    }
    if (c == 0) {
#pragma unroll
        for (int r = 0; r < 4; ++r) sRedM[it][jh][q * 4 + r] = m4[r];
    }
    __syncthreads();

    float mf[4], sum4[4];
#pragma unroll
    for (int r = 0; r < 4; ++r) {
        mf[r]   = fmaxf(sRedM[it][0][q * 4 + r], sRedM[it][1][q * 4 + r]);
        sum4[r] = 0.f;
    }
#pragma unroll
    for (int t = 0; t < 16; ++t) {
        const int j = jbase + t * 16 + c;
#pragma unroll
        for (int r = 0; r < 4; ++r) {
            float p = __expf(S[t][r] - mf[r]);   // NEG_INF path underflows to 0
            sum4[r] += p;
            sAlpha[it * 16 + q * 4 + r][j] = (_Float16)p;
        }
    }
#pragma unroll
    for (int r = 0; r < 4; ++r) {
#pragma unroll
        for (int off = 1; off < 16; off <<= 1)
            sum4[r] += __shfl_xor(sum4[r], off, 64);
    }
    if (c == 0) {
#pragma unroll
        for (int r = 0; r < 4; ++r) sRedS[it][jh][q * 4 + r] = sum4[r];
    }
    __syncthreads();   // covers sAlpha + sRedS writes

    // ---------------- phase 3: out = alpha @ H, wave = 64-d quarter ----------------
    const _Float16* Htb = h16t + (size_t)b * DD * NN;
    const int dq0 = wave * 64;
    v4f o[2][4];
#pragma unroll
    for (int t2 = 0; t2 < 2; ++t2)
#pragma unroll
        for (int nt = 0; nt < 4; ++nt) o[t2][nt] = (v4f){0.f, 0.f, 0.f, 0.f};

#pragma unroll
    for (int ks = 0; ks < 16; ++ks) {
        const int j0 = ks * 32;
        half8 af[2];
#pragma unroll
        for (int t2 = 0; t2 < 2; ++t2)
            af[t2] = *(const half8*)(&sAlpha[t2 * 16 + c][j0 + q * 8]);
        half8 bf[4];
#pragma unroll
        for (int nt = 0; nt < 4; ++nt)
            bf[nt] = *(const half8*)(Htb + (size_t)(dq0 + nt * 16 + c) * NN + j0 + q * 8);
#pragma unroll
        for (int t2 = 0; t2 < 2; ++t2)
#pragma unroll
            for (int nt = 0; nt < 4; ++nt)
                o[t2][nt] = __builtin_amdgcn_mfma_f32_16x16x32_f16(af[t2], bf[nt], o[t2][nt], 0, 0, 0);
    }

    float* outb = out + (size_t)b * NN * DD;
#pragma unroll
    for (int t2 = 0; t2 < 2; ++t2) {
#pragma unroll
        for (int r = 0; r < 4; ++r) {
            const int irow = t2 * 16 + q * 4 + r;
            const float rinv = 1.f / (sRedS[t2][0][q * 4 + r] + sRedS[t2][1][q * 4 + r]);
#pragma unroll
            for (int nt = 0; nt < 4; ++nt) {
                const int d = dq0 + nt * 16 + c;
                outb[(size_t)(i0 + irow) * DD + d] = o[t2][nt][r] * rinv;
            }
        }
    }
}

// ---------------- launcher ----------------
extern "C" void kernel_launch(void* const* d_in, const int* in_sizes, int n_in,
                              void* d_out, int out_size, void* d_ws, size_t ws_size,
                              hipStream_t stream) {
    const float* hidden = (const float*)d_in[0];
    const int*   adjp   = (const int*)d_in[1];
    const float* a0     = (const float*)d_in[2];
    const float* a1     = (const float*)d_in[3];
    const float* a2     = (const float*)d_in[4];
    const float* a3     = (const float*)d_in[5];
    float* outp = (float*)d_out;

    _Float16* h16  = (_Float16*)d_ws;
    _Float16* h16t = h16 + (size_t)BB * NN * DD;

    dim3 g1(DD / 32, NN / 32, BB);
    cvt_kernel<<<g1, 256, 0, stream>>>(hidden, h16, h16t);

    gat_kernel<<<BB * (NN / 32), 256, 0, stream>>>(h16, h16t, adjp, a0, a1, a2, a3, outp);
}